// Round 4
// baseline (87.211 us; speedup 1.0000x reference)
//
#include <hip/hip_runtime.h>

// PolyConvFrame: out = sum_L tanh(theta_L) * J_L(adj), elementwise cubic.
// Horner: out = ((c3*x + c2)*x + c1)*x + c0.
// Jacobi coefficients are compile-time constants (a=1, b=0.2); only
// tanh(thetas) is runtime -> folded into the kernel per-thread.
//
// R3->R4: (1) drop the "memory" clobber on the streaming store so the
// compiler can hoist next-iteration loads above this iteration's stores
// (software pipelining; buffers are __restrict__/non-aliasing);
// (2) unroll x8 (128 B of loads in flight per thread); (3) grid 4096.
// R2/R3 established FETCH is pinned at adj/2 by memory-side MALL
// allocation policy (not software-controllable) -> only issue-side left.

namespace {
constexpr double da = 1.0, db = 0.2;
constexpr double P10 = 0.5 * (da - db);
constexpr double P11 = 0.5 * (da + db + 2.0);
constexpr double A2 = (4.0 + da + db) * (3.0 + da + db) / (4.0 * (2.0 + da + db));
constexpr double B2 = (3.0 + da + db) * (da * da - db * db) /
                      (4.0 * (2.0 + da + db) * (2.0 + da + db));
constexpr double C2 = (1.0 + da) * (1.0 + db) * (4.0 + da + db) /
                      (2.0 * (2.0 + da + db) * (2.0 + da + db));
constexpr double Q2 = A2 * P11;
constexpr double Q1 = A2 * P10 + B2 * P11;
constexpr double Q0 = B2 * P10 - C2;
constexpr double A3 = (6.0 + da + db) * (5.0 + da + db) / (6.0 * (3.0 + da + db));
constexpr double B3 = (5.0 + da + db) * (da * da - db * db) /
                      (6.0 * (3.0 + da + db) * (4.0 + da + db));
constexpr double C3 = (2.0 + da) * (2.0 + db) * (6.0 + da + db) /
                      (3.0 * (3.0 + da + db) * (4.0 + da + db));
constexpr double R3 = A3 * Q2;
constexpr double R2 = A3 * Q1 + B3 * Q2;
constexpr double R1 = A3 * Q0 + B3 * Q1 - C3 * P11;
constexpr double R0 = B3 * Q0 - C3 * P10;
}  // namespace

typedef float v4f __attribute__((ext_vector_type(4)));

__device__ __forceinline__ v4f horner4(v4f x, float c0, float c1, float c2, float c3) {
    v4f y = c3 * x + c2;
    y = y * x + c1;
    y = y * x + c0;
    return y;
}

// Streaming store (L2 bypass + non-temporal). NO "memory" clobber: out/in
// are __restrict__ non-aliasing, and we want the compiler free to hoist
// subsequent loads above these stores for software pipelining.
__device__ __forceinline__ void stream_store4(v4f* p, v4f v) {
    asm volatile("global_store_dwordx4 %0, %1, off sc0 sc1 nt"
                 :: "v"(p), "v"(v));
}

__global__ __launch_bounds__(256) void poly_eval_kernel(
        const float* __restrict__ in, float* __restrict__ out,
        const float* __restrict__ thetas, int n4) {
    float t0 = tanhf(thetas[0]);
    float t1 = tanhf(thetas[1]);
    float t2 = tanhf(thetas[2]);
    float t3 = tanhf(thetas[3]);
    float c0 = t0 + t1 * (float)P10 + t2 * (float)Q0 + t3 * (float)R0;
    float c1 =      t1 * (float)P11 + t2 * (float)Q1 + t3 * (float)R1;
    float c2 =                        t2 * (float)Q2 + t3 * (float)R2;
    float c3 =                                         t3 * (float)R3;

    const v4f* __restrict__ in4 = (const v4f*)in;
    v4f* __restrict__ out4 = (v4f*)out;

    int tid = blockIdx.x * blockDim.x + threadIdx.x;
    int stride = gridDim.x * blockDim.x;

    int i = tid;
    // Unrolled x8: 8 independent coalesced 16B loads (128 B) in flight.
    for (; i + 7 * stride < n4; i += 8 * stride) {
        v4f x0 = in4[i];
        v4f x1 = in4[i + stride];
        v4f x2 = in4[i + 2 * stride];
        v4f x3 = in4[i + 3 * stride];
        v4f x4 = in4[i + 4 * stride];
        v4f x5 = in4[i + 5 * stride];
        v4f x6 = in4[i + 6 * stride];
        v4f x7 = in4[i + 7 * stride];
        stream_store4(out4 + i,              horner4(x0, c0, c1, c2, c3));
        stream_store4(out4 + i + stride,     horner4(x1, c0, c1, c2, c3));
        stream_store4(out4 + i + 2 * stride, horner4(x2, c0, c1, c2, c3));
        stream_store4(out4 + i + 3 * stride, horner4(x3, c0, c1, c2, c3));
        stream_store4(out4 + i + 4 * stride, horner4(x4, c0, c1, c2, c3));
        stream_store4(out4 + i + 5 * stride, horner4(x5, c0, c1, c2, c3));
        stream_store4(out4 + i + 6 * stride, horner4(x6, c0, c1, c2, c3));
        stream_store4(out4 + i + 7 * stride, horner4(x7, c0, c1, c2, c3));
    }
    for (; i < n4; i += stride) {
        v4f x = in4[i];
        stream_store4(out4 + i, horner4(x, c0, c1, c2, c3));
    }
}

extern "C" void kernel_launch(void* const* d_in, const int* in_sizes, int n_in,
                              void* d_out, int out_size, void* d_ws, size_t ws_size,
                              hipStream_t stream) {
    const float* adj    = (const float*)d_in[0];
    const float* thetas = (const float*)d_in[1];
    float* out = (float*)d_out;

    int n  = out_size;   // 8192*8192 = 67108864, divisible by 4
    int n4 = n / 4;
    int block = 256;
    int grid = 4096;     // 16 wg/CU worth of work queued; grid-stride loop
    poly_eval_kernel<<<grid, block, 0, stream>>>(adj, out, thetas, n4);
}